// Round 7
// baseline (102.206 us; speedup 1.0000x reference)
//
#include <hip/hip_runtime.h>

// Problem constants (reference: S, B, D, MAX_LEN, P = 4096, 64, 256, 4096, 8)
#define S_LEN 4096
#define BATCH 64
#define DIM 256
#define NPEAK 8
#define ROW4 (BATCH * DIM / 4)      // 4096 float4 per s-row
#define KITERS (ROW4 / 256)         // 16 iterations per block

typedef float f32x4 __attribute__((ext_vector_type(4)));

// One block per s-row. out[s,b,d] = x[s,b,d] + pe[s,d] + cnt(s,b)*table[s,d].
//
// pe[s][d4] / table[s][d4] hoisted to registers (s fixed per block, d4 fixed
// per thread). Peak counts built once in an LDS prologue. Steady loop is
// copy-shaped.
//
// Lessons: r2 unroll-4 on strided layout regressed; r4 XCD swizzle regressed;
// r5 row-block structure won (104->100.6). This round: depth-2 software
// pipeline on the contiguous streaming loop (load k+1 in flight before
// store k) — the only remaining per-wave issue-gap candidate.
__global__ __launch_bounds__(256) void fused_pe_peak_kernel(
    const f32x4* __restrict__ x,
    const int*   __restrict__ peaks,
    const f32x4* __restrict__ pe,
    const f32x4* __restrict__ table,
    f32x4* __restrict__ out)
{
    const int s = blockIdx.x;                 // 0 .. S_LEN-1
    const int t = threadIdx.x;
    const int d4 = t & 63;
    const int w  = t >> 6;                    // wave id 0..3

    __shared__ int cnt[BATCH];
    __shared__ int anypeak;
    if (t < BATCH) cnt[t] = 0;
    if (t == 0) anypeak = 0;
    __syncthreads();
    #pragma unroll
    for (int j = t; j < BATCH * NPEAK; j += 256) {   // 2 probes/thread
        if (peaks[j] == s) {                          // invalid peaks never match
            atomicAdd(&cnt[j >> 3], 1);               // duplicates accumulate
            anypeak = 1;                              // benign race (all write 1)
        }
    }
    __syncthreads();

    const f32x4 pv = pe[(s << 6) + d4];       // once per block
    const size_t base = (size_t)s * ROW4;

    if (!anypeak) {
        // Common path (~87% of rows): depth-2 pipelined copy + registered add.
        f32x4 cur = __builtin_nontemporal_load(&x[base + t]);
        #pragma unroll 1
        for (int k = 0; k < KITERS - 1; ++k) {
            f32x4 nxt = __builtin_nontemporal_load(&x[base + (k + 1) * 256 + t]);
            __builtin_nontemporal_store(cur + pv, &out[base + k * 256 + t]);
            cur = nxt;
        }
        __builtin_nontemporal_store(cur + pv, &out[base + (KITERS - 1) * 256 + t]);
    } else {
        const f32x4 tv = table[(s << 6) + d4];
        #pragma unroll 1
        for (int k = 0; k < KITERS; ++k) {
            const size_t i = base + k * 256 + t;
            f32x4 o = __builtin_nontemporal_load(&x[i]) + pv;
            const int c = cnt[4 * k + w];     // wave-uniform LDS broadcast
            if (c) o += (float)c * tv;
            __builtin_nontemporal_store(o, &out[i]);
        }
    }
}

extern "C" void kernel_launch(void* const* d_in, const int* in_sizes, int n_in,
                              void* d_out, int out_size, void* d_ws, size_t ws_size,
                              hipStream_t stream) {
    const float* x     = (const float*)d_in[0];   // [S, B, D] f32
    const int* peaks   = (const int*)d_in[1];     // [B, P] i32
    const float* pe    = (const float*)d_in[2];   // [MAX_LEN, 1, D] f32
    const float* table = (const float*)d_in[3];   // [MAX_LEN, D] f32

    fused_pe_peak_kernel<<<S_LEN, 256, 0, stream>>>(
        (const f32x4*)x, peaks, (const f32x4*)pe, (const f32x4*)table,
        (f32x4*)d_out);
}

// Round 8
// 101.990 us; speedup vs baseline: 1.0021x; 1.0021x over previous
//
#include <hip/hip_runtime.h>

// Problem constants (reference: S, B, D, MAX_LEN, P = 4096, 64, 256, 4096, 8)
#define S_LEN 4096
#define BATCH 64
#define DIM 256
#define NPEAK 8
#define ROW4 (BATCH * DIM / 4)      // 4096 float4 per s-row
#define KITERS (ROW4 / 256)         // 16 iterations per block

typedef float f32x4 __attribute__((ext_vector_type(4)));

// FINAL (round-5 structure, best measured: 100.65 us ~= 85.5% of copy ceiling).
// One block per s-row. out[s,b,d] = x[s,b,d] + pe[s,d] + cnt(s,b)*table[s,d].
//
// pe[s][d4] / table[s][d4] hoisted to registers (s fixed per block, d4 = t&63
// fixed per thread). Peak counts built once in a tiny LDS prologue from the
// 2 KB L2-hot peaks array. Steady loop is copy-shaped: nt-load, packed add,
// nt-store.
//
// Exhausted levers (keep for posterity):
//   r2 explicit unroll-4 (strided): -6%   r3 cached stores: neutral
//   r4 XCD swizzle: -4%                   r6 depth-2 pipeline: -1.5%
//   r5 row-block structure: +3.3% (this kernel)
__global__ __launch_bounds__(256) void fused_pe_peak_kernel(
    const f32x4* __restrict__ x,
    const int*   __restrict__ peaks,
    const f32x4* __restrict__ pe,
    const f32x4* __restrict__ table,
    f32x4* __restrict__ out)
{
    const int s = blockIdx.x;                 // 0 .. S_LEN-1
    const int t = threadIdx.x;
    const int d4 = t & 63;
    const int w  = t >> 6;                    // wave id 0..3

    __shared__ int cnt[BATCH];
    __shared__ int anypeak;
    if (t < BATCH) cnt[t] = 0;
    if (t == 0) anypeak = 0;
    __syncthreads();
    #pragma unroll
    for (int j = t; j < BATCH * NPEAK; j += 256) {   // 2 probes/thread
        if (peaks[j] == s) {                          // invalid peaks never match
            atomicAdd(&cnt[j >> 3], 1);               // duplicates accumulate
            anypeak = 1;                              // benign race (all write 1)
        }
    }
    __syncthreads();

    const f32x4 pv = pe[(s << 6) + d4];       // once per block
    const size_t base = (size_t)s * ROW4;

    if (!anypeak) {
        // Common path (~87% of rows): pure copy + registered add.
        #pragma unroll 1
        for (int k = 0; k < KITERS; ++k) {
            const size_t i = base + k * 256 + t;
            f32x4 o = __builtin_nontemporal_load(&x[i]) + pv;
            __builtin_nontemporal_store(o, &out[i]);
        }
    } else {
        const f32x4 tv = table[(s << 6) + d4];
        #pragma unroll 1
        for (int k = 0; k < KITERS; ++k) {
            const size_t i = base + k * 256 + t;
            f32x4 o = __builtin_nontemporal_load(&x[i]) + pv;
            const int c = cnt[4 * k + w];     // wave-uniform LDS broadcast
            if (c) o += (float)c * tv;
            __builtin_nontemporal_store(o, &out[i]);
        }
    }
}

extern "C" void kernel_launch(void* const* d_in, const int* in_sizes, int n_in,
                              void* d_out, int out_size, void* d_ws, size_t ws_size,
                              hipStream_t stream) {
    const float* x     = (const float*)d_in[0];   // [S, B, D] f32
    const int* peaks   = (const int*)d_in[1];     // [B, P] i32
    const float* pe    = (const float*)d_in[2];   // [MAX_LEN, 1, D] f32
    const float* table = (const float*)d_in[3];   // [MAX_LEN, D] f32

    fused_pe_peak_kernel<<<S_LEN, 256, 0, stream>>>(
        (const f32x4*)x, peaks, (const f32x4*)pe, (const f32x4*)table,
        (f32x4*)d_out);
}